// Round 2
// baseline (235.366 us; speedup 1.0000x reference)
//
#include <hip/hip_runtime.h>
#include <stdint.h>

// Binarized ConvNet: conv1(5x5,s2,p2,1->32) + BN + sign ; conv2(4x4,s2,p2,32->64)
// + BN + sign ; fc(4096->10) + BN.  All binary ops done as XOR+popcount on packed
// bits; BN stats accumulated as exact integer sums (sharded atomics).

#define NB 8192

// ---- ws layout ----
#define OFF_C1  ((size_t)0)                    // int8  [NB][196][32]
#define SZ_C1   ((size_t)NB*6272)
#define OFF_C2  (OFF_C1 + SZ_C1)               // int16 [NB][64][64]
#define SZ_C2   ((size_t)NB*4096*2)
#define OFF_FC  (OFF_C2 + SZ_C2)               // int32 [NB][10]
#define SZ_FC   ((size_t)NB*10*4)
#define OFF_S1  (OFF_FC + SZ_FC)               // int   [8][32][2]
#define OFF_S2  (OFF_S1 + 2048)                // ull   [8][64][2]
#define OFF_S3  (OFF_S2 + 8192)                // ull   [8][10][2]
#define OFF_AB1 (OFF_S3 + 2048)                // float a1[32] b1[32]
#define OFF_AB2 (OFF_AB1 + 256)                // float a2[64] b2[64]
#define OFF_W2B (OFF_AB2 + 512)                // ull   [64][4][2]
#define OFF_W3B (OFF_W2B + 4096)               // ull   [10][64]

// ------------------------------------------------------------------
// K1: conv1 (binary) + integer BN1 stats.  1 block = 8 images.
// ------------------------------------------------------------------
__global__ __launch_bounds__(256) void k1_conv1(
    const float* __restrict__ x, const float* __restrict__ w1,
    int8_t* __restrict__ c1out, int* __restrict__ stats1)
{
    __shared__ uint32_t rb[28];          // row bits, pre-shifted <<2
    __shared__ uint32_t wfilt[32];       // 25-bit filters
    __shared__ uint32_t outbuf[196*8];   // int8 [196][32] packed as dwords
    __shared__ int lsum[32], lsq[32];
    const int tid = threadIdx.x;

    if (tid < 32) {
        uint32_t f = 0u;
        #pragma unroll
        for (int q = 0; q < 25; ++q) f |= (w1[tid*25 + q] > 0.f ? 1u : 0u) << q;
        wfilt[tid] = f;
        lsum[tid] = 0; lsq[tid] = 0;
    }
    const int n0 = blockIdx.x * 8;
    for (int im = 0; im < 8; ++im) {
        const int n = n0 + im;
        __syncthreads();
        // build 28 row-bit words via ballot (28 rows x 32 col-slots, 896 = 14 waves)
        for (int idx = tid; idx < 896; idx += 256) {
            const int r = idx >> 5, c = idx & 31;
            bool pred = false;
            if (c < 28) pred = x[(size_t)n*784 + r*28 + c] > 0.f;
            const unsigned long long m = __ballot(pred);
            const int l = idx & 63;
            if (l == 0)       rb[r] = ((uint32_t)m & 0x0FFFFFFFu) << 2;
            else if (l == 32) rb[r] = ((uint32_t)(m >> 32) & 0x0FFFFFFFu) << 2;
        }
        __syncthreads();
        if (tid < 196) {
            const int p = tid;
            const int i = p / 14, j = p - i*14;
            const uint32_t cmask = (j == 0) ? 0x1Cu : (j == 13) ? 0x0Fu : 0x1Fu;
            uint32_t win = 0u, vm = 0u;
            const int sh = 2*j;
            #pragma unroll
            for (int u = 0; u < 5; ++u) {
                const int r = 2*i + u - 2;
                if (r >= 0 && r < 28) {
                    win |= ((rb[r] >> sh) & 31u) << (5*u);
                    vm  |= cmask << (5*u);
                }
            }
            const int nv = __popc(vm);
            uint32_t dw[8];
            #pragma unroll
            for (int d = 0; d < 8; ++d) dw[d] = 0u;
            #pragma unroll
            for (int c = 0; c < 32; ++c) {
                const int diff = __popc((win ^ wfilt[c]) & vm);
                const int o = nv - 2*diff;
                dw[c >> 2] |= (uint32_t)(o & 255) << (8*(c & 3));
            }
            #pragma unroll
            for (int d = 0; d < 8; ++d) outbuf[p*8 + d] = dw[d];
        }
        __syncthreads();
        {   // coalesced global write, layout [n][pos][ch]
            int4* dst = (int4*)(c1out + (size_t)n*6272);
            const int4* srcb = (const int4*)outbuf;
            for (int idx = tid; idx < 392; idx += 256) dst[idx] = srcb[idx];
        }
        {   // per-channel integer stats
            const int c = tid & 31, g = tid >> 5;
            const int8_t* ob = (const int8_t*)outbuf;
            int s = 0, q = 0;
            for (int p = g; p < 196; p += 8) {
                const int v = ob[p*32 + c];
                s += v; q += v*v;
            }
            atomicAdd(&lsum[c], s);
            atomicAdd(&lsq[c], q);
        }
    }
    __syncthreads();
    if (tid < 32) {
        const int shard = blockIdx.x & 7;
        atomicAdd(&stats1[(shard*32 + tid)*2 + 0], lsum[tid]);
        atomicAdd(&stats1[(shard*32 + tid)*2 + 1], lsq[tid]);
    }
}

// ------------------------------------------------------------------
// K2: reduce BN1 stats -> (a1,b1); pack w2 and w3 sign bits.
// ------------------------------------------------------------------
__global__ __launch_bounds__(256) void k2_prep(
    const float* __restrict__ w2, const float* __restrict__ w3,
    const float* __restrict__ gm1, const float* __restrict__ bt1,
    const int* __restrict__ stats1, float* __restrict__ ab1,
    unsigned long long* __restrict__ w2b, unsigned long long* __restrict__ w3b)
{
    const int tid = threadIdx.x;
    if (tid < 32) {
        long long s = 0, q = 0;
        for (int sh = 0; sh < 8; ++sh) {
            s += stats1[(sh*32 + tid)*2 + 0];
            q += stats1[(sh*32 + tid)*2 + 1];
        }
        const double N = 8192.0 * 196.0;
        const double mean = (double)s / N;
        const double var  = (double)q / N - mean*mean;
        const double a = (double)gm1[tid] / sqrt(var + 1e-5);
        ab1[tid]      = (float)a;
        ab1[32 + tid] = (float)((double)bt1[tid] - mean*a);
    }
    // w2 bits: [k][u][pair] over 32 channels, lo=first col, hi=second col
    for (int t = tid; t < 512; t += 256) {
        const int k = t >> 3, u = (t >> 1) & 3, pr = t & 1;
        uint32_t lo = 0u, hi = 0u;
        for (int c = 0; c < 32; ++c) {
            const float* wp = w2 + (((k*32 + c)*4 + u)*4 + 2*pr);
            lo |= (wp[0] > 0.f ? 1u : 0u) << c;
            hi |= (wp[1] > 0.f ? 1u : 0u) << c;
        }
        w2b[t] = (unsigned long long)lo | ((unsigned long long)hi << 32);
    }
    // w3 bits: [m][word]
    for (int t = tid; t < 640; t += 256) {
        const int m = t >> 6, w = t & 63;
        unsigned long long bits = 0ull;
        const float* wp = w3 + (size_t)m*4096 + (size_t)w*64;
        for (int k = 0; k < 64; ++k)
            bits |= (unsigned long long)(wp[k] > 0.f ? 1u : 0u) << k;
        w3b[t] = bits;
    }
}

// ------------------------------------------------------------------
// K3: binarize conv1 out (BN1 fused), conv2 via xor+popc, BN2 stats.
// 1 block = 4 images, one wave per image in compute phase.
// ------------------------------------------------------------------
__global__ __launch_bounds__(256) void k3_conv2(
    const int8_t* __restrict__ c1out, const float* __restrict__ ab1,
    const unsigned long long* __restrict__ w2b,
    int16_t* __restrict__ c2out, unsigned long long* __restrict__ stats2)
{
    __shared__ uint32_t Bw[4][14][16];        // channel-bit words per position
    __shared__ unsigned long long W[64][8];   // [k][2u+pair]
    __shared__ float sa1[32], sb1[32];
    __shared__ int ssum[64], ssq[64];
    const int tid = threadIdx.x;
    const int n0 = blockIdx.x * 4;

    for (int t = tid; t < 512; t += 256) ((unsigned long long*)W)[t] = w2b[t];
    if (tid < 32) { sa1[tid] = ab1[tid]; sb1[tid] = ab1[32 + tid]; }
    if (tid < 64) { ssum[tid] = 0; ssq[tid] = 0; }
    __syncthreads();   // <<< FIX: sa1/sb1 must be visible before the pack loop reads them
    // pack: binarize 32 channels per position into one word
    for (int t = tid; t < 4*196; t += 256) {
        const int im = t / 196, p = t - im*196;
        const int r = p / 14, c = p - r*14;
        const uint32_t* src = (const uint32_t*)(c1out + ((size_t)(n0+im)*196 + p)*32);
        uint32_t bits = 0u;
        #pragma unroll
        for (int d = 0; d < 8; ++d) {
            const uint32_t dwv = src[d];
            #pragma unroll
            for (int qq = 0; qq < 4; ++qq) {
                const int v = (int)(dwv << (24 - 8*qq)) >> 24;
                const int ch = d*4 + qq;
                bits |= (fmaf(sa1[ch], (float)v, sb1[ch]) > 0.f ? 1u : 0u) << ch;
            }
        }
        Bw[im][r][c] = bits;
    }
    __syncthreads();
    const int im = tid >> 6, lane = tid & 63;
    const int i = lane >> 3, j = lane & 7;
    const int n = n0 + im;
    unsigned long long V[4][2], M[4][2];
    int nvp = 0;
    #pragma unroll
    for (int u = 0; u < 4; ++u) {
        const int r = 2*i + u - 2;
        const bool rv = (r >= 0) && (r < 14);
        const int rc = rv ? r : 0;
        const bool av = rv && (j >= 1);
        const bool bv = rv && (j <= 6);
        const int cA = (j >= 1) ? (2*j - 2) : 0;
        const int cB = (j <= 6) ? (2*j) : 0;
        V[u][0] = *(const unsigned long long*)&Bw[im][rc][cA];
        V[u][1] = *(const unsigned long long*)&Bw[im][rc][cB];
        M[u][0] = av ? ~0ull : 0ull;
        M[u][1] = bv ? ~0ull : 0ull;
        nvp += (int)av + (int)bv;
    }
    int16_t* outp = c2out + (size_t)n*4096 + lane;
    #pragma unroll 4
    for (int k = 0; k < 64; ++k) {
        int D = 0;
        #pragma unroll
        for (int u = 0; u < 4; ++u) {
            D += __popcll((V[u][0] ^ W[k][2*u+0]) & M[u][0]);
            D += __popcll((V[u][1] ^ W[k][2*u+1]) & M[u][1]);
        }
        outp[(size_t)k*64] = (int16_t)(64*nvp - 2*D);
    }
    __syncthreads();
    {   // stats pass: re-read (L1/L2 resident) per channel
        const int k = tid & 63, sub = tid >> 6;
        const int16_t* src = c2out + ((size_t)(n0+sub)*64 + k)*64;
        int s = 0, q = 0;
        #pragma unroll 8
        for (int p = 0; p < 64; ++p) { const int v = src[p]; s += v; q += v*v; }
        atomicAdd(&ssum[k], s);
        atomicAdd(&ssq[k], q);
    }
    __syncthreads();
    if (tid < 64) {
        const int shard = blockIdx.x & 7;
        atomicAdd(&stats2[(shard*64 + tid)*2 + 0], (unsigned long long)(long long)ssum[tid]);
        atomicAdd(&stats2[(shard*64 + tid)*2 + 1], (unsigned long long)(long long)ssq[tid]);
    }
}

// ------------------------------------------------------------------
// K4: reduce BN2 stats -> (a2,b2)
// ------------------------------------------------------------------
__global__ __launch_bounds__(64) void k4_prep2(
    const float* __restrict__ gm2, const float* __restrict__ bt2,
    const unsigned long long* __restrict__ stats2, float* __restrict__ ab2)
{
    const int tid = threadIdx.x;
    if (tid < 64) {
        long long s = 0, q = 0;
        for (int sh = 0; sh < 8; ++sh) {
            s += (long long)stats2[(sh*64 + tid)*2 + 0];
            q += (long long)stats2[(sh*64 + tid)*2 + 1];
        }
        const double N = 8192.0 * 64.0;
        const double mean = (double)s / N;
        const double var  = (double)q / N - mean*mean;
        const double a = (double)gm2[tid] / sqrt(var + 1e-5);
        ab2[tid]      = (float)a;
        ab2[64 + tid] = (float)((double)bt2[tid] - mean*a);
    }
}

// ------------------------------------------------------------------
// K5: binarize conv2 out (BN2 fused) via ballot, fc via xor+popc, BN3 stats.
// 1 block = 16 images (4 per wave).
// ------------------------------------------------------------------
__global__ __launch_bounds__(256) void k5_fc(
    const int16_t* __restrict__ c2out, const float* __restrict__ ab2,
    const unsigned long long* __restrict__ w3b,
    int* __restrict__ fc, unsigned long long* __restrict__ stats3)
{
    __shared__ unsigned long long w3s[640];
    __shared__ float sa2[64], sb2[64];
    __shared__ int fco[16][10];
    __shared__ int s3[10], q3[10];
    const int tid = threadIdx.x;
    for (int t = tid; t < 640; t += 256) w3s[t] = w3b[t];
    if (tid < 64) { sa2[tid] = ab2[tid]; sb2[tid] = ab2[64 + tid]; }
    if (tid < 10) { s3[tid] = 0; q3[tid] = 0; }
    __syncthreads();
    const int wv = tid >> 6, lane = tid & 63;
    const int n0 = blockIdx.x * 16;
    for (int it = 0; it < 4; ++it) {
        const int li = wv*4 + it;
        const size_t base = ((size_t)(n0 + li))*4096;
        unsigned long long myw = 0ull;
        for (int w = 0; w < 64; ++w) {
            const int v = c2out[base + (size_t)w*64 + lane];
            const bool z = fmaf(sa2[w], (float)v, sb2[w]) > 0.f;
            const unsigned long long bal = __ballot(z);
            if (lane == w) myw = bal;
        }
        #pragma unroll
        for (int m = 0; m < 10; ++m) {
            int part = __popcll(myw ^ w3s[m*64 + lane]);
            part += __shfl_xor(part, 32);
            part += __shfl_xor(part, 16);
            part += __shfl_xor(part, 8);
            part += __shfl_xor(part, 4);
            part += __shfl_xor(part, 2);
            part += __shfl_xor(part, 1);
            if (lane == 0) fco[li][m] = 4096 - 2*part;
        }
    }
    __syncthreads();
    if (tid < 160) {
        const int li = tid / 10, m = tid - li*10;
        const int o = fco[li][m];
        fc[(size_t)(n0 + li)*10 + m] = o;
        atomicAdd(&s3[m], o);
        atomicAdd(&q3[m], o*o);
    }
    __syncthreads();
    if (tid < 10) {
        const int shard = blockIdx.x & 7;
        atomicAdd(&stats3[(shard*10 + tid)*2 + 0], (unsigned long long)(long long)s3[tid]);
        atomicAdd(&stats3[(shard*10 + tid)*2 + 1], (unsigned long long)(long long)q3[tid]);
    }
}

// ------------------------------------------------------------------
// K6: reduce BN3 stats (redundantly per block) + apply -> d_out (fp32)
// ------------------------------------------------------------------
__global__ __launch_bounds__(256) void k6_apply(
    const int* __restrict__ fc, const float* __restrict__ gm3,
    const float* __restrict__ bt3, const unsigned long long* __restrict__ stats3,
    float* __restrict__ out)
{
    __shared__ float a3[10], b3[10];
    const int tid = threadIdx.x;
    if (tid < 10) {
        long long s = 0, q = 0;
        for (int sh = 0; sh < 8; ++sh) {
            s += (long long)stats3[(sh*10 + tid)*2 + 0];
            q += (long long)stats3[(sh*10 + tid)*2 + 1];
        }
        const double N = 8192.0;
        const double mean = (double)s / N;
        const double var  = (double)q / N - mean*mean;
        const double a = (double)gm3[tid] / sqrt(var + 1e-5);
        a3[tid] = (float)a;
        b3[tid] = (float)((double)bt3[tid] - mean*a);
    }
    __syncthreads();
    const int e = blockIdx.x*256 + tid;
    if (e < NB*10) {
        const int m = e % 10;
        out[e] = fmaf(a3[m], (float)fc[e], b3[m]);
    }
}

extern "C" void kernel_launch(void* const* d_in, const int* in_sizes, int n_in,
                              void* d_out, int out_size, void* d_ws, size_t ws_size,
                              hipStream_t stream)
{
    const float* x   = (const float*)d_in[0];
    const float* w1  = (const float*)d_in[1];
    const float* gm1 = (const float*)d_in[2];
    const float* bt1 = (const float*)d_in[3];
    const float* w2  = (const float*)d_in[4];
    const float* gm2 = (const float*)d_in[5];
    const float* bt2 = (const float*)d_in[6];
    const float* w3  = (const float*)d_in[7];
    const float* gm3 = (const float*)d_in[8];
    const float* bt3 = (const float*)d_in[9];
    char* ws = (char*)d_ws;
    int8_t*  c1o = (int8_t*)(ws + OFF_C1);
    int16_t* c2o = (int16_t*)(ws + OFF_C2);
    int*     fcb = (int*)(ws + OFF_FC);
    int*     s1  = (int*)(ws + OFF_S1);
    unsigned long long* s2 = (unsigned long long*)(ws + OFF_S2);
    unsigned long long* s3 = (unsigned long long*)(ws + OFF_S3);
    float* ab1 = (float*)(ws + OFF_AB1);
    float* ab2 = (float*)(ws + OFF_AB2);
    unsigned long long* w2bp = (unsigned long long*)(ws + OFF_W2B);
    unsigned long long* w3bp = (unsigned long long*)(ws + OFF_W3B);

    hipMemsetAsync(ws + OFF_S1, 0, 12288, stream);
    k1_conv1<<<1024, 256, 0, stream>>>(x, w1, c1o, s1);
    k2_prep <<<1,    256, 0, stream>>>(w2, w3, gm1, bt1, s1, ab1, w2bp, w3bp);
    k3_conv2<<<2048, 256, 0, stream>>>(c1o, ab1, w2bp, c2o, s2);
    k4_prep2<<<1,     64, 0, stream>>>(gm2, bt2, s2, ab2);
    k5_fc   <<<512,  256, 0, stream>>>(c2o, ab2, w3bp, fcb, s3);
    k6_apply<<<320,  256, 0, stream>>>(fcb, gm3, bt3, s3, (float*)d_out);
}

// Round 3
// 226.196 us; speedup vs baseline: 1.0405x; 1.0405x over previous
//
#include <hip/hip_runtime.h>
#include <stdint.h>

// Binarized ConvNet, all binary ops as XOR+popcount on packed bits.
// BN stats as exact integer sums (sharded atomics); BN+sign folded into
// exact per-channel integer thresholds (computed in double).

#define NB 8192
typedef unsigned long long ull;

// ---- ws layout ----
#define OFF_C1  ((size_t)0)                    // int8 [NB][196][32]
#define SZ_C1   ((size_t)NB*6272)
#define OFF_C2  (OFF_C1 + SZ_C1)               // int8 [NB][64pos][64ch]  (stores o/2)
#define SZ_C2   ((size_t)NB*4096)
#define OFF_FC  (OFF_C2 + SZ_C2)               // int32 [NB][10]
#define SZ_FC   ((size_t)NB*10*4)
#define OFF_S1  (OFF_FC + SZ_FC)               // int  [8][32][2]   2048 B
#define OFF_S2  (OFF_S1 + 2048)                // ull  [8][64][2]   8192 B
#define OFF_S3  (OFF_S2 + 8192)                // ull  [8][10][2]   (pad 2048)
#define OFF_TH1 (OFF_S3 + 2048)                // int T1[32] + flip1 at [32]
#define OFF_W2B (OFF_TH1 + 256)                // ull w2bT[8][64]  (word-idx major)
#define OFF_W3B (OFF_W2B + 4096)               // ull w3b[10][64]  word=pos, bits=ch

// exact integer threshold: bit = (v >= T) ^ flip  <=>  s*v + t > 0
__device__ inline void mk_thresh(double s, double t, int &T, int &flip) {
    if (s > 0.0) {
        int v = (int)floor(-t / s) - 2;
        for (int c = 0; c < 6; ++c) { if (s * (double)v + t > 0.0) break; ++v; }
        T = v; flip = 0;
    } else if (s < 0.0) {
        int v = (int)floor(-t / s) - 2;
        for (int c = 0; c < 6; ++c) { if (!(s * (double)v + t > 0.0)) break; ++v; }
        T = v; flip = 1;
    } else { T = (-2147483647 - 1); flip = (t > 0.0) ? 0 : 1; }
}

// ------------------------------------------------------------------
// K1: conv1 (binary) + integer BN1 stats.  1 block = 4 images.
// ------------------------------------------------------------------
__global__ __launch_bounds__(256) void k1_conv1(
    const float* __restrict__ x, const float* __restrict__ w1,
    int8_t* __restrict__ c1out, int* __restrict__ stats1)
{
    __shared__ uint32_t rb[28];          // row bits, pre-shifted <<2
    __shared__ uint32_t wfilt[32];       // 25-bit filters
    __shared__ uint32_t outbuf[196*8];   // int8 [196][32] as dwords
    __shared__ int lsum[32], lsq[32];
    const int tid = threadIdx.x;

    if (tid < 32) {
        uint32_t f = 0u;
        #pragma unroll
        for (int q = 0; q < 25; ++q) f |= (w1[tid*25 + q] > 0.f ? 1u : 0u) << q;
        wfilt[tid] = f;
        lsum[tid] = 0; lsq[tid] = 0;
    }
    const int n0 = blockIdx.x * 4;
    for (int im = 0; im < 4; ++im) {
        const int n = n0 + im;
        __syncthreads();
        for (int idx = tid; idx < 896; idx += 256) {
            const int r = idx >> 5, c = idx & 31;
            bool pred = false;
            if (c < 28) pred = x[(size_t)n*784 + r*28 + c] > 0.f;
            const ull m = __ballot(pred);
            const int l = idx & 63;
            if (l == 0)       rb[r] = ((uint32_t)m & 0x0FFFFFFFu) << 2;
            else if (l == 32) rb[r] = ((uint32_t)(m >> 32) & 0x0FFFFFFFu) << 2;
        }
        __syncthreads();
        if (tid < 196) {
            const int p = tid;
            const int i = p / 14, j = p - i*14;
            const uint32_t cmask = (j == 0) ? 0x1Cu : (j == 13) ? 0x0Fu : 0x1Fu;
            uint32_t win = 0u, vm = 0u;
            const int sh = 2*j;
            #pragma unroll
            for (int u = 0; u < 5; ++u) {
                const int r = 2*i + u - 2;
                if (r >= 0 && r < 28) {
                    win |= ((rb[r] >> sh) & 31u) << (5*u);
                    vm  |= cmask << (5*u);
                }
            }
            const int nv = __popc(vm);
            uint32_t dw[8];
            #pragma unroll
            for (int d = 0; d < 8; ++d) dw[d] = 0u;
            #pragma unroll
            for (int c = 0; c < 32; ++c) {
                const int diff = __popc((win ^ wfilt[c]) & vm);
                const int o = nv - 2*diff;
                dw[c >> 2] |= (uint32_t)(o & 255) << (8*(c & 3));
            }
            #pragma unroll
            for (int d = 0; d < 8; ++d) outbuf[p*8 + d] = dw[d];
        }
        __syncthreads();
        {   // coalesced global write, layout [n][pos][ch]
            int4* dst = (int4*)(c1out + (size_t)n*6272);
            const int4* srcb = (const int4*)outbuf;
            for (int idx = tid; idx < 392; idx += 256) dst[idx] = srcb[idx];
        }
        {   // per-channel integer stats
            const int c = tid & 31, g = tid >> 5;
            const int8_t* ob = (const int8_t*)outbuf;
            int s = 0, q = 0;
            for (int p = g; p < 196; p += 8) {
                const int v = ob[p*32 + c];
                s += v; q += v*v;
            }
            atomicAdd(&lsum[c], s);
            atomicAdd(&lsq[c], q);
        }
    }
    __syncthreads();
    if (tid < 32) {
        const int shard = blockIdx.x & 7;
        atomicAdd(&stats1[(shard*32 + tid)*2 + 0], lsum[tid]);
        atomicAdd(&stats1[(shard*32 + tid)*2 + 1], lsq[tid]);
    }
}

// ------------------------------------------------------------------
// K2: BN1 stats -> integer thresholds T1/flip1; pack w2 (word-major) and w3
// (word=pos, bits=ch).
// ------------------------------------------------------------------
__global__ __launch_bounds__(256) void k2_prep(
    const float* __restrict__ w2, const float* __restrict__ w3,
    const float* __restrict__ gm1, const float* __restrict__ bt1,
    const int* __restrict__ stats1, int* __restrict__ th1,
    ull* __restrict__ w2bT, ull* __restrict__ w3b)
{
    const int tid = threadIdx.x;
    if (tid < 32) {
        long long s = 0, q = 0;
        for (int sh = 0; sh < 8; ++sh) {
            s += stats1[(sh*32 + tid)*2 + 0];
            q += stats1[(sh*32 + tid)*2 + 1];
        }
        const double N = 8192.0 * 196.0;
        const double mean = (double)s / N;
        const double var  = (double)q / N - mean*mean;
        const double a = (double)gm1[tid] / sqrt(var + 1e-5);
        const double b = (double)bt1[tid] - mean*a;
        int T, fl; mk_thresh(a, b, T, fl);
        th1[tid] = T;
        const ull bm = __ballot(fl != 0);
        if (tid == 0) th1[32] = (int)(uint32_t)bm;
    }
    // w2 bits, word-idx major: w2bT[idx*64 + k], idx = u*2+pr
    for (int t = tid; t < 512; t += 256) {
        const int idx = t >> 6, k = t & 63;
        const int u = idx >> 1, pr = idx & 1;
        uint32_t lo = 0u, hi = 0u;
        for (int c = 0; c < 32; ++c) {
            const float* wp = w2 + (((k*32 + c)*4 + u)*4 + 2*pr);
            lo |= (wp[0] > 0.f ? 1u : 0u) << c;
            hi |= (wp[1] > 0.f ? 1u : 0u) << c;
        }
        w2bT[t] = (ull)lo | ((ull)hi << 32);
    }
    // w3 bits: word = position p, bit k = channel k  (flat idx = k*64+p)
    for (int t = tid; t < 640; t += 256) {
        const int m = t >> 6, p = t & 63;
        ull bits = 0ull;
        for (int k = 0; k < 64; ++k)
            bits |= (ull)(w3[(size_t)m*4096 + (size_t)k*64 + p] > 0.f ? 1 : 0) << k;
        w3b[t] = bits;
    }
}

// ------------------------------------------------------------------
// K3: binarize c1 (int threshold), conv2 xor+popc with lanes=channels
// (uniform masks -> skip invalid words), register BN2 stats, int8 o/2 out.
// 1 block = 4 images (1 per wave).
// ------------------------------------------------------------------
__global__ __launch_bounds__(256) void k3_conv2(
    const int8_t* __restrict__ c1out, const int* __restrict__ th1,
    const ull* __restrict__ w2bT,
    int8_t* __restrict__ c2out, ull* __restrict__ stats2)
{
    __shared__ ull BwU[4][14][8];     // packed input bits, [im][row][col-pair]
    __shared__ ull sW[512];
    __shared__ int sT1[33];
    __shared__ int ssum[64], ssq[64];
    const int tid = threadIdx.x;
    const int n0 = blockIdx.x * 4;

    for (int t = tid; t < 512; t += 256) sW[t] = w2bT[t];
    if (tid < 33) sT1[tid] = th1[tid];
    if (tid < 64) { ssum[tid] = 0; ssq[tid] = 0; }
    __syncthreads();
    const uint32_t flip1 = (uint32_t)sT1[32];
    for (int t = tid; t < 784; t += 256) {
        const int im = t / 196, p = t - im*196;
        const int r = p / 14, c = p - r*14;
        const uint32_t* src = (const uint32_t*)(c1out + ((size_t)(n0+im)*196 + p)*32);
        uint32_t bits = 0u;
        #pragma unroll
        for (int d = 0; d < 8; ++d) {
            const uint32_t dwv = src[d];
            #pragma unroll
            for (int qq = 0; qq < 4; ++qq) {
                const int ch = d*4 + qq;
                const int v = (int)((int8_t)(dwv >> (8*qq)));
                bits |= (v >= sT1[ch]) ? (1u << ch) : 0u;
            }
        }
        ((uint32_t*)&BwU[im][r][0])[c] = bits ^ flip1;
    }
    __syncthreads();
    const int im = tid >> 6, lane = tid & 63;
    const int n = n0 + im;
    ull W[8];
    #pragma unroll
    for (int idx = 0; idx < 8; ++idx) W[idx] = sW[idx*64 + lane];
    int s = 0, q = 0;
    int8_t* outp = c2out + (size_t)n*4096 + lane;
    for (int p = 0; p < 64; ++p) {          // uniform loop: i,j scalar
        const int i = p >> 3, j = p & 7;
        int D = 0, nv = 0;
        #pragma unroll
        for (int u = 0; u < 4; ++u) {
            const int r = 2*i + u - 2;
            if (r < 0 || r > 13) continue;   // wave-uniform skip
            const ull* row = &BwU[im][r][0];
            if (j >= 1) { D += __popcll(row[j-1] ^ W[2*u+0]); ++nv; }
            if (j <= 6) { D += __popcll(row[j]   ^ W[2*u+1]); ++nv; }
        }
        const int o = 32*nv - D;             // = full_o / 2 (exact, fits int8)
        outp[p*64] = (int8_t)o;
        s += o; q += o*o;
    }
    atomicAdd(&ssum[lane], s);
    atomicAdd(&ssq[lane], q);
    __syncthreads();
    if (tid < 64) {
        const int shard = blockIdx.x & 7;
        atomicAdd(&stats2[(shard*64 + tid)*2 + 0], (ull)(long long)ssum[tid]);
        atomicAdd(&stats2[(shard*64 + tid)*2 + 1], (ull)(long long)ssq[tid]);
    }
}

// ------------------------------------------------------------------
// K5: fold BN2-prep (per block), binarize via int threshold + ballot,
// fc xor+popc, BN3 stats.  1 block = 4 images (1 per wave).
// ------------------------------------------------------------------
__global__ __launch_bounds__(256) void k5_fc(
    const int8_t* __restrict__ c2o, const float* __restrict__ gm2,
    const float* __restrict__ bt2, const ull* __restrict__ stats2,
    const ull* __restrict__ w3b,
    int* __restrict__ fc, ull* __restrict__ stats3)
{
    __shared__ ull w3s[640];
    __shared__ int sT2[64];
    __shared__ ull sflip2;
    __shared__ int fco[4][10];
    __shared__ int s3[10], q3[10];
    const int tid = threadIdx.x;
    const int lane = tid & 63, wv = tid >> 6;
    for (int t = tid; t < 640; t += 256) w3s[t] = w3b[t];
    if (tid < 10) { s3[tid] = 0; q3[tid] = 0; }
    if (tid < 64) {   // wave 0: BN2 -> integer thresholds (values are o/2)
        long long ss = 0, qq = 0;
        for (int sh = 0; sh < 8; ++sh) {
            ss += (long long)stats2[(sh*64 + tid)*2 + 0];
            qq += (long long)stats2[(sh*64 + tid)*2 + 1];
        }
        const double N = 8192.0 * 64.0;
        const double mh = (double)ss / N;
        const double vh = (double)qq / N - mh*mh;
        const double mean = 2.0*mh, var = 4.0*vh;
        const double a = (double)gm2[tid] / sqrt(var + 1e-5);
        const double b = (double)bt2[tid] - mean*a;
        int T, fl; mk_thresh(2.0*a, b, T, fl);
        sT2[tid] = T;
        const ull bm = __ballot(fl != 0);
        if (tid == 0) sflip2 = bm;
    }
    __syncthreads();
    const int T2 = sT2[lane];
    const ull flip2 = sflip2;
    const int n = blockIdx.x*4 + wv;
    const size_t base = (size_t)n * 4096;
    ull myw = 0ull;
    for (int p8 = 0; p8 < 64; p8 += 8) {     // 8 loads in flight per group
        int v[8];
        #pragma unroll
        for (int u = 0; u < 8; ++u) v[u] = c2o[base + (size_t)(p8+u)*64 + lane];
        #pragma unroll
        for (int u = 0; u < 8; ++u) {
            const ull bal = __ballot(v[u] >= T2) ^ flip2;
            if (lane == p8 + u) myw = bal;
        }
    }
    #pragma unroll
    for (int m = 0; m < 10; ++m) {
        int part = __popcll(myw ^ w3s[m*64 + lane]);
        part += __shfl_xor(part, 32);
        part += __shfl_xor(part, 16);
        part += __shfl_xor(part, 8);
        part += __shfl_xor(part, 4);
        part += __shfl_xor(part, 2);
        part += __shfl_xor(part, 1);
        if (lane == 0) fco[wv][m] = 4096 - 2*part;
    }
    __syncthreads();
    if (tid < 40) {
        const int li = tid / 10, m = tid - li*10;
        const int o = fco[li][m];
        fc[(size_t)(blockIdx.x*4 + li)*10 + m] = o;
        atomicAdd(&s3[m], o);
        atomicAdd(&q3[m], o*o);
    }
    __syncthreads();
    if (tid < 10) {
        const int shard = blockIdx.x & 7;
        atomicAdd(&stats3[(shard*10 + tid)*2 + 0], (ull)(long long)s3[tid]);
        atomicAdd(&stats3[(shard*10 + tid)*2 + 1], (ull)(long long)q3[tid]);
    }
}

// ------------------------------------------------------------------
// K6: reduce BN3 stats (per block, redundant) + apply -> d_out (fp32)
// ------------------------------------------------------------------
__global__ __launch_bounds__(256) void k6_apply(
    const int* __restrict__ fc, const float* __restrict__ gm3,
    const float* __restrict__ bt3, const ull* __restrict__ stats3,
    float* __restrict__ out)
{
    __shared__ float a3[10], b3[10];
    const int tid = threadIdx.x;
    if (tid < 10) {
        long long s = 0, q = 0;
        for (int sh = 0; sh < 8; ++sh) {
            s += (long long)stats3[(sh*10 + tid)*2 + 0];
            q += (long long)stats3[(sh*10 + tid)*2 + 1];
        }
        const double N = 8192.0;
        const double mean = (double)s / N;
        const double var  = (double)q / N - mean*mean;
        const double a = (double)gm3[tid] / sqrt(var + 1e-5);
        a3[tid] = (float)a;
        b3[tid] = (float)((double)bt3[tid] - mean*a);
    }
    __syncthreads();
    const int e = blockIdx.x*256 + tid;
    if (e < NB*10) {
        const int m = e % 10;
        out[e] = fmaf(a3[m], (float)fc[e], b3[m]);
    }
}

extern "C" void kernel_launch(void* const* d_in, const int* in_sizes, int n_in,
                              void* d_out, int out_size, void* d_ws, size_t ws_size,
                              hipStream_t stream)
{
    const float* x   = (const float*)d_in[0];
    const float* w1  = (const float*)d_in[1];
    const float* gm1 = (const float*)d_in[2];
    const float* bt1 = (const float*)d_in[3];
    const float* w2  = (const float*)d_in[4];
    const float* gm2 = (const float*)d_in[5];
    const float* bt2 = (const float*)d_in[6];
    const float* w3  = (const float*)d_in[7];
    const float* gm3 = (const float*)d_in[8];
    const float* bt3 = (const float*)d_in[9];
    char* ws = (char*)d_ws;
    int8_t* c1o = (int8_t*)(ws + OFF_C1);
    int8_t* c2o = (int8_t*)(ws + OFF_C2);
    int*    fcb = (int*)(ws + OFF_FC);
    int*    s1  = (int*)(ws + OFF_S1);
    ull*    s2  = (ull*)(ws + OFF_S2);
    ull*    s3  = (ull*)(ws + OFF_S3);
    int*    th1 = (int*)(ws + OFF_TH1);
    ull*    w2bp = (ull*)(ws + OFF_W2B);
    ull*    w3bp = (ull*)(ws + OFF_W3B);

    hipMemsetAsync(ws + OFF_S1, 0, 12288, stream);
    k1_conv1<<<2048, 256, 0, stream>>>(x, w1, c1o, s1);
    k2_prep <<<1,    256, 0, stream>>>(w2, w3, gm1, bt1, s1, th1, w2bp, w3bp);
    k3_conv2<<<2048, 256, 0, stream>>>(c1o, th1, w2bp, c2o, s2);
    k5_fc   <<<2048, 256, 0, stream>>>(c2o, gm2, bt2, s2, w3bp, fcb, s3);
    k6_apply<<<320,  256, 0, stream>>>(fcb, gm3, bt3, s3, (float*)d_out);
}

// Round 4
// 184.615 us; speedup vs baseline: 1.2749x; 1.2252x over previous
//
#include <hip/hip_runtime.h>
#include <stdint.h>

// Binarized ConvNet via XOR+popcount on packed bits.
// BN stats = exact integer sums (sharded global atomics); BN+sign folded into
// exact per-channel integer thresholds, computed redundantly per consumer block.

#define NB 8192
typedef unsigned long long ull;

// ---- ws layout ----
#define OFF_C1  ((size_t)0)                    // int8 [NB][196pos][32ch]
#define SZ_C1   ((size_t)NB*6272)
#define OFF_C2  (OFF_C1 + SZ_C1)               // int8 [NB][64ch][64pos] (stores o/2)
#define SZ_C2   ((size_t)NB*4096)
#define OFF_FC  (OFF_C2 + SZ_C2)               // int32 [NB][10]
#define SZ_FC   ((size_t)NB*10*4)
#define OFF_S1  (OFF_FC + SZ_FC)               // int  [8][32][2]   2048 B
#define OFF_S2  (OFF_S1 + 2048)                // ull  [8][64][2]   8192 B
#define OFF_S3  (OFF_S2 + 8192)                // ull  [8][10][2]   (pad 2048)
#define OFF_W2B (OFF_S3 + 2048)                // ull w2bT[8][64] (word-idx major)
#define OFF_W3B (OFF_W2B + 4096)               // ull w3b[10][64ch], bit=pos

// exact integer threshold: bit = (v >= T)  (flip via mask)  <=>  s*v + t > 0
__device__ inline void mk_thresh(double s, double t, int &T, int &flip) {
    if (s > 0.0) {
        int v = (int)floor(-t / s) - 2;
        for (int c = 0; c < 6; ++c) { if (s * (double)v + t > 0.0) break; ++v; }
        T = v; flip = 0;
    } else if (s < 0.0) {
        int v = (int)floor(-t / s) - 2;
        for (int c = 0; c < 6; ++c) { if (!(s * (double)v + t > 0.0)) break; ++v; }
        T = v; flip = 1;
    } else { T = -200; flip = (t > 0.0) ? 0 : 1; }
}
__device__ inline int clampT(int T, int lim) {
    return (T < -lim) ? -lim : (T > lim) ? lim : T;
}

// ------------------------------------------------------------------
// KA: conv1 (binary) + integer BN1 stats.  1 wave = 1 image, 4/block.
// Block 2048 packs w2/w3 sign bits instead (removes old k2 kernel).
// ------------------------------------------------------------------
__global__ __launch_bounds__(256) void kA_conv1(
    const float* __restrict__ x, const float* __restrict__ w1,
    const float* __restrict__ w2, const float* __restrict__ w3,
    int8_t* __restrict__ c1out, int* __restrict__ stats1,
    ull* __restrict__ w2bT, ull* __restrict__ w3b)
{
    const int tid = threadIdx.x, lane = tid & 63, wv = tid >> 6;

    if (blockIdx.x == 2048) {   // ---- weight packer block ----
        // w3: word (m,ch), bit p = sign(w3[m,ch*64+p]); ballot over lane=p
        for (int m = wv; m < 10; m += 4) {
            const float* wp = w3 + (size_t)m*4096;
            ull mine = 0ull;
            for (int ch = 0; ch < 64; ++ch) {
                const ull bal = __ballot(wp[(size_t)ch*64 + lane] > 0.f);
                if (lane == ch) mine = bal;
            }
            w3b[m*64 + lane] = mine;
        }
        // w2 word (idx=(u,pr), k): lo = col 2pr, hi = col 2pr+1 over 32 in-ch
        for (int t = tid; t < 512; t += 256) {
            const int idx = t >> 6, k = t & 63;
            const int u = idx >> 1, pr = idx & 1;
            uint32_t lo = 0u, hi = 0u;
            for (int c = 0; c < 32; ++c) {
                const float* wp = w2 + (((k*32 + c)*4 + u)*4 + 2*pr);
                lo |= (wp[0] > 0.f ? 1u : 0u) << c;
                hi |= (wp[1] > 0.f ? 1u : 0u) << c;
            }
            w2bT[t] = (ull)lo | ((ull)hi << 32);
        }
        return;
    }

    __shared__ ull sxb[4][16];              // 784 sign bits + pad
    __shared__ uint32_t wfilt[32];          // 25-bit filters
    __shared__ uint32_t outb[4][1568];      // int8 [196][32] as dwords, per wave
    __shared__ int lsum[32], lsq[32];

    if (tid < 32) {
        uint32_t f = 0u;
        #pragma unroll
        for (int q = 0; q < 25; ++q) f |= (w1[tid*25 + q] > 0.f ? 1u : 0u) << q;
        wfilt[tid] = f;
        lsum[tid] = 0; lsq[tid] = 0;
    }
    const int n = blockIdx.x*4 + wv;
    // phase A: pack 784 input sign bits (13 ballot rounds, coalesced loads)
    #pragma unroll
    for (int t = 0; t < 13; ++t) {
        const int idx = t*64 + lane;
        const float v = (idx < 784) ? x[(size_t)n*784 + idx] : -1.f;
        const ull bal = __ballot(v > 0.f);
        if (lane == t) sxb[wv][t] = bal;
    }
    if (lane == 13) sxb[wv][13] = 0ull;
    __syncthreads();
    // phase B: each lane computes up to 4 positions, 32 channels each
    for (int t = 0; t < 4; ++t) {
        const int p = t*64 + lane;
        if (p < 196) {
            const int i = p / 14, j = p - i*14;
            const uint32_t cmask = (j == 0) ? 0x1Cu : (j == 13) ? 0x0Fu : 0x1Fu;
            uint32_t win = 0u, vm = 0u;
            #pragma unroll
            for (int u = 0; u < 5; ++u) {
                const int r = 2*i + u - 2;
                if (r >= 0 && r < 28) {
                    const int bp = 28*r, w0 = bp >> 6, sh = bp & 63;
                    const ull a = sxb[wv][w0], b = sxb[wv][w0+1];
                    uint32_t row = (uint32_t)((a >> sh) | ((b << 1) << (63 - sh)));
                    row = (row & 0x0FFFFFFFu) << 2;
                    win |= ((row >> (2*j)) & 31u) << (5*u);
                    vm  |= cmask << (5*u);
                }
            }
            const int nv = __popc(vm);
            uint32_t dw[8];
            #pragma unroll
            for (int d = 0; d < 8; ++d) dw[d] = 0u;
            #pragma unroll
            for (int c = 0; c < 32; ++c) {
                const int diff = __popc((win ^ wfilt[c]) & vm);
                const int o = nv - 2*diff;
                dw[c >> 2] |= (uint32_t)(o & 255) << (8*(c & 3));
            }
            #pragma unroll
            for (int d = 0; d < 8; ++d) outb[wv][p*8 + d] = dw[d];
        }
    }
    __syncthreads();
    {   // coalesced write [n][pos][ch]
        int4* dst = (int4*)(c1out + (size_t)n*6272);
        const int4* src = (const int4*)&outb[wv][0];
        #pragma unroll
        for (int t = 0; t < 7; ++t) {
            const int idx = t*64 + lane;
            if (idx < 392) dst[idx] = src[idx];
        }
    }
    {   // per-channel integer stats (lane = ch + 32*half)
        const int ch = lane & 31, half = lane >> 5;
        const int8_t* ob = (const int8_t*)&outb[wv][0];
        int s = 0, q = 0;
        for (int p = half*98; p < half*98 + 98; ++p) {
            const int v = ob[p*32 + ch];
            s += v; q += v*v;
        }
        s += __shfl_xor(s, 32);
        q += __shfl_xor(q, 32);
        if (lane < 32) { atomicAdd(&lsum[lane], s); atomicAdd(&lsq[lane], q); }
    }
    __syncthreads();
    if (tid < 32) {
        const int shard = blockIdx.x & 7;
        atomicAdd(&stats1[(shard*32 + tid)*2 + 0], lsum[tid]);
        atomicAdd(&stats1[(shard*32 + tid)*2 + 1], lsq[tid]);
    }
}

// ------------------------------------------------------------------
// KB: BN1 thresholds (per-block redundant), binarize c1, conv2 xor+popc
// (lane=ch, fully unrolled), register BN2 stats, int8 o/2 out [n][ch][pos].
// 1 block = 4 images (1 per wave).
// ------------------------------------------------------------------
__global__ __launch_bounds__(256) void kB_conv2(
    const int8_t* __restrict__ c1out, const int* __restrict__ stats1,
    const float* __restrict__ gm1, const float* __restrict__ bt1,
    const ull* __restrict__ w2bT,
    int8_t* __restrict__ c2out, ull* __restrict__ stats2)
{
    __shared__ ull BwU[4][14][8];       // packed input bits [im][row][col-pair]
    __shared__ ull sW[512];
    __shared__ int sT1[32];
    __shared__ uint32_t sFlip1;
    __shared__ uint32_t cw[4][64][16];  // staged output dwords [im][ch][pos/4]
    __shared__ int ssum[64], ssq[64];
    const int tid = threadIdx.x, lane = tid & 63, wv = tid >> 6;
    const int n0 = blockIdx.x * 4;

    for (int t = tid; t < 512; t += 256) sW[t] = w2bT[t];
    if (tid < 64) { ssum[tid] = 0; ssq[tid] = 0; }
    if (tid < 32) {     // redundant per-block BN1 threshold computation
        long long s = 0, q = 0;
        for (int sh = 0; sh < 8; ++sh) {
            s += stats1[(sh*32 + tid)*2 + 0];
            q += stats1[(sh*32 + tid)*2 + 1];
        }
        const double N = 8192.0 * 196.0;
        const double mean = (double)s / N;
        const double var  = (double)q / N - mean*mean;
        const double a = (double)gm1[tid] / sqrt(var + 1e-5);
        const double b = (double)bt1[tid] - mean*a;
        int T, fl; mk_thresh(a, b, T, fl);
        sT1[tid] = clampT(T, 26);
        const ull bm = __ballot(fl != 0);
        if (tid == 0) sFlip1 = (uint32_t)bm;
    }
    __syncthreads();
    const uint32_t flipn1 = ~sFlip1;
    // pack phase: binarize 32 channels/position into one word (negated bits)
    for (int t = tid; t < 784; t += 256) {
        const int im = t / 196, p = t - im*196;
        const int r = p / 14, c = p - r*14;
        const uint4* src = (const uint4*)(c1out + ((size_t)(n0+im)*196 + p)*32);
        const uint4 lo4 = src[0], hi4 = src[1];
        const uint32_t wsrc[8] = {lo4.x, lo4.y, lo4.z, lo4.w, hi4.x, hi4.y, hi4.z, hi4.w};
        uint32_t neg = 0u;
        #pragma unroll
        for (int d = 0; d < 8; ++d) {
            #pragma unroll
            for (int qq = 0; qq < 4; ++qq) {
                const int ch = d*4 + qq;
                const int v = (int)((int8_t)(wsrc[d] >> (8*qq)));
                neg |= ((uint32_t)(v - sT1[ch]) >> 31) << ch;   // 1 iff v<T
            }
        }
        ((uint32_t*)&BwU[im][r][0])[c] = neg ^ flipn1;
    }
    __syncthreads();
    // compute phase: lane = out-channel, fully unrolled over 64 positions
    ull W[8];
    #pragma unroll
    for (int idx = 0; idx < 8; ++idx) W[idx] = sW[idx*64 + lane];
    int s = 0, q = 0;
    #pragma unroll
    for (int i = 0; i < 8; ++i) {
        uint32_t packA = 0u;
        #pragma unroll
        for (int j = 0; j < 8; ++j) {
            int D = 0, nw = 0;
            #pragma unroll
            for (int u = 0; u < 4; ++u) {
                const int r = 2*i + u - 2;
                if (r < 0 || r > 13) continue;           // compile-time
                const ull* row = &BwU[wv][r][0];
                if (j >= 1) { D += __popcll(row[j-1] ^ W[2*u+0]); ++nw; }
                if (j <= 6) { D += __popcll(row[j]   ^ W[2*u+1]); ++nw; }
            }
            const int o = 32*nw - D;                     // = full/2, exact
            s += o; q += o*o;
            packA |= (uint32_t)(o & 255) << (8*(j & 3));
            if ((j & 3) == 3) { cw[wv][lane][2*i + (j >> 2)] = packA; packA = 0u; }
        }
    }
    atomicAdd(&ssum[lane], s);
    atomicAdd(&ssq[lane], q);
    __syncthreads();
    {   // coalesced writeout [n][ch][pos]: 4KB contiguous per image
        const int n = n0 + wv;
        int4* dst = (int4*)(c2out + (size_t)n*4096);
        const int4* src = (const int4*)&cw[wv][0][0];
        #pragma unroll
        for (int t = 0; t < 4; ++t) dst[t*64 + lane] = src[t*64 + lane];
    }
    if (tid < 64) {
        const int shard = blockIdx.x & 7;
        atomicAdd(&stats2[(shard*64 + tid)*2 + 0], (ull)(long long)ssum[tid]);
        atomicAdd(&stats2[(shard*64 + tid)*2 + 1], (ull)(long long)ssq[tid]);
    }
}

// ------------------------------------------------------------------
// KC: BN2 thresholds (per-block), binarize (arithmetic, no ballot),
// fc xor+popc, packed shuffle reduction, BN3 stats.  1 wave = 1 image.
// ------------------------------------------------------------------
__global__ __launch_bounds__(256) void kC_fc(
    const int8_t* __restrict__ c2o, const float* __restrict__ gm2,
    const float* __restrict__ bt2, const ull* __restrict__ stats2,
    const ull* __restrict__ w3b,
    int* __restrict__ fc, ull* __restrict__ stats3)
{
    __shared__ ull w3s[640];
    __shared__ int sT2[64];
    __shared__ ull sFlip2;
    __shared__ int fco[4][10];
    __shared__ int s3[10], q3[10];
    const int tid = threadIdx.x, lane = tid & 63, wv = tid >> 6;
    for (int t = tid; t < 640; t += 256) w3s[t] = w3b[t];
    if (tid < 10) { s3[tid] = 0; q3[tid] = 0; }
    if (tid < 64) {     // redundant BN2 thresholds (on o/2 values)
        long long ss = 0, qq = 0;
        for (int sh = 0; sh < 8; ++sh) {
            ss += (long long)stats2[(sh*64 + tid)*2 + 0];
            qq += (long long)stats2[(sh*64 + tid)*2 + 1];
        }
        const double N = 8192.0 * 64.0;
        const double mh = (double)ss / N;
        const double vh = (double)qq / N - mh*mh;
        const double a = (double)gm2[tid] / sqrt(4.0*vh + 1e-5);
        const double b = (double)bt2[tid] - 2.0*mh*a;
        int T, fl; mk_thresh(2.0*a, b, T, fl);
        sT2[tid] = clampT(T, 200);
        const ull bm = __ballot(fl != 0);
        if (tid == 0) sFlip2 = bm;
    }
    __syncthreads();
    const int T2 = sT2[lane];
    const ull flipn2 = ~sFlip2;
    const int n = blockIdx.x*4 + wv;
    // load own channel's 64 bytes, build bit-word arithmetically
    const uint4* src = (const uint4*)(c2o + (size_t)n*4096 + lane*64);
    uint32_t neglo = 0u, neghi = 0u;
    #pragma unroll
    for (int r4 = 0; r4 < 4; ++r4) {
        const uint4 v4 = src[r4];
        const uint32_t wsrc[4] = {v4.x, v4.y, v4.z, v4.w};
        #pragma unroll
        for (int c = 0; c < 4; ++c) {
            #pragma unroll
            for (int b = 0; b < 4; ++b) {
                const int p = r4*16 + c*4 + b;
                const int v = (int)((int8_t)(wsrc[c] >> (8*b)));
                const uint32_t bit = (uint32_t)(v - T2) >> 31;   // 1 iff v<T
                if (p < 32) neglo |= bit << p; else neghi |= bit << (p - 32);
            }
        }
    }
    const ull myw = ((ull)neglo | ((ull)neghi << 32)) ^ flipn2;
    // 10 outputs: popc of mismatch, packed 2-per-dword shuffle reduction
    uint32_t pk[5];
    #pragma unroll
    for (int t = 0; t < 5; ++t) {
        const uint32_t pa = (uint32_t)__popcll(myw ^ w3s[(2*t+0)*64 + lane]);
        const uint32_t pb = (uint32_t)__popcll(myw ^ w3s[(2*t+1)*64 + lane]);
        pk[t] = pa | (pb << 16);
    }
    #pragma unroll
    for (int off = 32; off >= 1; off >>= 1) {
        #pragma unroll
        for (int t = 0; t < 5; ++t) pk[t] += __shfl_xor(pk[t], off);
    }
    if (lane == 0) {
        #pragma unroll
        for (int m = 0; m < 10; ++m) {
            const int tot = (pk[m >> 1] >> (16*(m & 1))) & 0xFFFF;
            fco[wv][m] = 4096 - 2*tot;
        }
    }
    __syncthreads();
    if (tid < 40) {
        const int li = tid / 10, m = tid - li*10;
        const int o = fco[li][m];
        fc[(size_t)(blockIdx.x*4 + li)*10 + m] = o;
        atomicAdd(&s3[m], o);
        atomicAdd(&q3[m], o*o);
    }
    __syncthreads();
    if (tid < 10) {
        const int shard = blockIdx.x & 7;
        atomicAdd(&stats3[(shard*10 + tid)*2 + 0], (ull)(long long)s3[tid]);
        atomicAdd(&stats3[(shard*10 + tid)*2 + 1], (ull)(long long)q3[tid]);
    }
}

// ------------------------------------------------------------------
// KD: reduce BN3 stats (per block, redundant) + apply -> d_out (fp32)
// ------------------------------------------------------------------
__global__ __launch_bounds__(256) void kD_apply(
    const int* __restrict__ fc, const float* __restrict__ gm3,
    const float* __restrict__ bt3, const ull* __restrict__ stats3,
    float* __restrict__ out)
{
    __shared__ float a3[10], b3[10];
    const int tid = threadIdx.x;
    if (tid < 10) {
        long long s = 0, q = 0;
        for (int sh = 0; sh < 8; ++sh) {
            s += (long long)stats3[(sh*10 + tid)*2 + 0];
            q += (long long)stats3[(sh*10 + tid)*2 + 1];
        }
        const double N = 8192.0;
        const double mean = (double)s / N;
        const double var  = (double)q / N - mean*mean;
        const double a = (double)gm3[tid] / sqrt(var + 1e-5);
        a3[tid] = (float)a;
        b3[tid] = (float)((double)bt3[tid] - mean*a);
    }
    __syncthreads();
    const int e = blockIdx.x*256 + tid;
    if (e < NB*10) {
        const int m = e % 10;
        out[e] = fmaf(a3[m], (float)fc[e], b3[m]);
    }
}

extern "C" void kernel_launch(void* const* d_in, const int* in_sizes, int n_in,
                              void* d_out, int out_size, void* d_ws, size_t ws_size,
                              hipStream_t stream)
{
    const float* x   = (const float*)d_in[0];
    const float* w1  = (const float*)d_in[1];
    const float* gm1 = (const float*)d_in[2];
    const float* bt1 = (const float*)d_in[3];
    const float* w2  = (const float*)d_in[4];
    const float* gm2 = (const float*)d_in[5];
    const float* bt2 = (const float*)d_in[6];
    const float* w3  = (const float*)d_in[7];
    const float* gm3 = (const float*)d_in[8];
    const float* bt3 = (const float*)d_in[9];
    char* ws = (char*)d_ws;
    int8_t* c1o = (int8_t*)(ws + OFF_C1);
    int8_t* c2o = (int8_t*)(ws + OFF_C2);
    int*    fcb = (int*)(ws + OFF_FC);
    int*    s1  = (int*)(ws + OFF_S1);
    ull*    s2  = (ull*)(ws + OFF_S2);
    ull*    s3  = (ull*)(ws + OFF_S3);
    ull*    w2bp = (ull*)(ws + OFF_W2B);
    ull*    w3bp = (ull*)(ws + OFF_W3B);

    hipMemsetAsync(ws + OFF_S1, 0, 12288, stream);
    kA_conv1<<<2049, 256, 0, stream>>>(x, w1, w2, w3, c1o, s1, w2bp, w3bp);
    kB_conv2<<<2048, 256, 0, stream>>>(c1o, s1, gm1, bt1, w2bp, c2o, s2);
    kC_fc   <<<2048, 256, 0, stream>>>(c2o, gm2, bt2, s2, w3bp, fcb, s3);
    kD_apply<<<320,  256, 0, stream>>>(fcb, gm3, bt3, s3, (float*)d_out);
}

// Round 5
// 181.606 us; speedup vs baseline: 1.2960x; 1.0166x over previous
//
#include <hip/hip_runtime.h>
#include <stdint.h>

// Binarized ConvNet via XOR+popcount on packed bits.
// BN stats = exact integer sums (sharded global atomics); BN+sign folded into
// exact per-channel integer thresholds, computed redundantly per consumer
// block/wave.  All heavy kernels are wave-independent (minimal barriers).

#define NB 8192
typedef unsigned long long ull;

// ---- ws layout ----
#define OFF_C1  ((size_t)0)                    // int8 [NB][196pos][32ch]
#define SZ_C1   ((size_t)NB*6272)
#define OFF_C2  (OFF_C1 + SZ_C1)               // int8 [NB][64ch][64pos] (stores o/2)
#define SZ_C2   ((size_t)NB*4096)
#define OFF_FC  (OFF_C2 + SZ_C2)               // int32 [NB][10]
#define SZ_FC   ((size_t)NB*10*4)
#define OFF_S1  (OFF_FC + SZ_FC)               // int  [8][32][2]   2048 B
#define OFF_S2  (OFF_S1 + 2048)                // ull  [8][64][2]   8192 B
#define OFF_S3  (OFF_S2 + 8192)                // ull  [8][10][2]   (pad 2048)
#define OFF_W2B (OFF_S3 + 2048)                // ull w2bT[8][64] (word-idx major)
#define OFF_W3B (OFF_W2B + 4096)               // ull w3b[10][64ch], bit=pos

// exact integer threshold: bit = (v >= T)  (flip via mask)  <=>  s*v + t > 0
__device__ inline void mk_thresh(double s, double t, int &T, int &flip) {
    if (s > 0.0) {
        int v = (int)floor(-t / s) - 2;
        for (int c = 0; c < 6; ++c) { if (s * (double)v + t > 0.0) break; ++v; }
        T = v; flip = 0;
    } else if (s < 0.0) {
        int v = (int)floor(-t / s) - 2;
        for (int c = 0; c < 6; ++c) { if (!(s * (double)v + t > 0.0)) break; ++v; }
        T = v; flip = 1;
    } else { T = -200; flip = (t > 0.0) ? 0 : 1; }
}
__device__ inline int clampT(int T, int lim) {
    return (T < -lim) ? -lim : (T > lim) ? lim : T;
}

// ------------------------------------------------------------------
// KA: conv1 (binary) + integer BN1 stats.  1 wave = 1 image, 4/block,
// wave-independent (2 barriers).  Block 2048 packs w2/w3 sign bits.
// ------------------------------------------------------------------
__global__ __launch_bounds__(256) void kA_conv1(
    const float* __restrict__ x, const float* __restrict__ w1,
    const float* __restrict__ w2, const float* __restrict__ w3,
    int8_t* __restrict__ c1out, int* __restrict__ stats1,
    ull* __restrict__ w2bT, ull* __restrict__ w3b)
{
    const int tid = threadIdx.x, lane = tid & 63, wv = tid >> 6;

    if (blockIdx.x == 2048) {   // ---- weight packer block ----
        for (int m = wv; m < 10; m += 4) {
            const float* wp = w3 + (size_t)m*4096;
            ull mine = 0ull;
            for (int ch = 0; ch < 64; ++ch) {
                const ull bal = __ballot(wp[(size_t)ch*64 + lane] > 0.f);
                if (lane == ch) mine = bal;
            }
            w3b[m*64 + lane] = mine;
        }
        for (int t = tid; t < 512; t += 256) {
            const int idx = t >> 6, k = t & 63;
            const int u = idx >> 1, pr = idx & 1;
            uint32_t lo = 0u, hi = 0u;
            for (int c = 0; c < 32; ++c) {
                const float* wp = w2 + (((k*32 + c)*4 + u)*4 + 2*pr);
                lo |= (wp[0] > 0.f ? 1u : 0u) << c;
                hi |= (wp[1] > 0.f ? 1u : 0u) << c;
            }
            w2bT[t] = (ull)lo | ((ull)hi << 32);
        }
        return;
    }

    __shared__ ull sxb[4][16];              // 784 sign bits, per wave
    __shared__ uint32_t wfilt[32];          // 25-bit filters
    __shared__ uint32_t outb[4][1568];      // int8 [196][32] as dwords, per wave
    __shared__ int lsum[32], lsq[32];

    if (tid < 32) {
        uint32_t f = 0u;
        #pragma unroll
        for (int q = 0; q < 25; ++q) f |= (w1[tid*25 + q] > 0.f ? 1u : 0u) << q;
        wfilt[tid] = f;
        lsum[tid] = 0; lsq[tid] = 0;
    }
    __syncthreads();          // barrier 1: wfilt + zeroed lsum visible
    const int n = blockIdx.x*4 + wv;
    // phase A: pack 784 input sign bits (13 ballot rounds) — wave-local
    #pragma unroll
    for (int t = 0; t < 13; ++t) {
        const int idx = t*64 + lane;
        const float v = (idx < 784) ? x[(size_t)n*784 + idx] : -1.f;
        const ull bal = __ballot(v > 0.f);
        if (lane == t) sxb[wv][t] = bal;
    }
    if (lane == 13) sxb[wv][13] = 0ull;
    // phase B: each lane computes up to 4 positions, 32 channels each
    for (int t = 0; t < 4; ++t) {
        const int p = t*64 + lane;
        if (p < 196) {
            const int i = p / 14, j = p - i*14;
            const uint32_t cmask = (j == 0) ? 0x1Cu : (j == 13) ? 0x0Fu : 0x1Fu;
            uint32_t win = 0u, vm = 0u;
            #pragma unroll
            for (int u = 0; u < 5; ++u) {
                const int r = 2*i + u - 2;
                if (r >= 0 && r < 28) {
                    const int bp = 28*r, w0 = bp >> 6, sh = bp & 63;
                    const ull a = sxb[wv][w0], b = sxb[wv][w0+1];
                    uint32_t row = (uint32_t)((a >> sh) | ((b << 1) << (63 - sh)));
                    row = (row & 0x0FFFFFFFu) << 2;
                    win |= ((row >> (2*j)) & 31u) << (5*u);
                    vm  |= cmask << (5*u);
                }
            }
            const int nv = __popc(vm);
            uint32_t dw[8];
            #pragma unroll
            for (int d = 0; d < 8; ++d) dw[d] = 0u;
            #pragma unroll
            for (int c = 0; c < 32; ++c) {
                const int diff = __popc((win ^ wfilt[c]) & vm);
                const int o = nv - 2*diff;
                dw[c >> 2] |= (uint32_t)(o & 255) << (8*(c & 3));
            }
            #pragma unroll
            for (int d = 0; d < 8; ++d) outb[wv][p*8 + d] = dw[d];
        }
    }
    {   // coalesced write [n][pos][ch] — wave-local
        int4* dst = (int4*)(c1out + (size_t)n*6272);
        const int4* src = (const int4*)&outb[wv][0];
        #pragma unroll
        for (int t = 0; t < 7; ++t) {
            const int idx = t*64 + lane;
            if (idx < 392) dst[idx] = src[idx];
        }
    }
    {   // per-channel integer stats (lane = ch + 32*half) — wave-local
        const int ch = lane & 31, half = lane >> 5;
        const int8_t* ob = (const int8_t*)&outb[wv][0];
        int s = 0, q = 0;
        for (int p = half*98; p < half*98 + 98; ++p) {
            const int v = ob[p*32 + ch];
            s += v; q += v*v;
        }
        s += __shfl_xor(s, 32);
        q += __shfl_xor(q, 32);
        if (lane < 32) { atomicAdd(&lsum[lane], s); atomicAdd(&lsq[lane], q); }
    }
    __syncthreads();          // barrier 2: all waves' stats in lsum/lsq
    if (tid < 32) {
        const int shard = blockIdx.x & 7;
        atomicAdd(&stats1[(shard*32 + tid)*2 + 0], lsum[tid]);
        atomicAdd(&stats1[(shard*32 + tid)*2 + 1], lsq[tid]);
    }
}

// ------------------------------------------------------------------
// KB: per-wave BN1 thresholds, binarize c1, conv2 xor+popc (lane=ch,
// fully unrolled), register BN2 stats, int8 o/2 out [n][ch][pos].
// 1 wave = 1 image; W operands from global; cw padded 17 (conflict-free).
// ------------------------------------------------------------------
__global__ __launch_bounds__(256) void kB_conv2(
    const int8_t* __restrict__ c1out, const int* __restrict__ stats1,
    const float* __restrict__ gm1, const float* __restrict__ bt1,
    const ull* __restrict__ w2bT,
    int8_t* __restrict__ c2out, ull* __restrict__ stats2)
{
    __shared__ ull BwU[4][14][8];       // packed input bits, per wave
    __shared__ int sT1[4][32];          // per-wave thresholds
    __shared__ uint32_t cw[4][64][17];  // staged out dwords, pad 17 -> no conflict
    __shared__ int ssum[64], ssq[64];
    const int tid = threadIdx.x, lane = tid & 63, wv = tid >> 6;
    const int n = blockIdx.x*4 + wv;

    // W fragments straight from global (coalesced, L2-hot)
    ull W[8];
    #pragma unroll
    for (int idx = 0; idx < 8; ++idx) W[idx] = w2bT[idx*64 + lane];

    if (tid < 64) { ssum[tid] = 0; ssq[tid] = 0; }
    // per-wave redundant BN1 threshold computation (lanes 0-31)
    int fl = 0;
    if (lane < 32) {
        long long s = 0, q = 0;
        for (int sh = 0; sh < 8; ++sh) {
            s += stats1[(sh*32 + lane)*2 + 0];
            q += stats1[(sh*32 + lane)*2 + 1];
        }
        const double N = 8192.0 * 196.0;
        const double mean = (double)s / N;
        const double var  = (double)q / N - mean*mean;
        const double a = (double)gm1[lane] / sqrt(var + 1e-5);
        const double b = (double)bt1[lane] - mean*a;
        int T; mk_thresh(a, b, T, fl);
        sT1[wv][lane] = clampT(T, 26);
    }
    const uint32_t flipn1 = ~(uint32_t)__ballot(fl != 0);
    __syncthreads();          // barrier 1: ssum zeros (thresholds are wave-local)

    // pack phase — wave-local: binarize own image's 196 positions
    for (int t = lane; t < 196; t += 64) {
        const int r = t / 14, c = t - r*14;
        const uint4* src = (const uint4*)(c1out + ((size_t)n*196 + t)*32);
        const uint4 lo4 = src[0], hi4 = src[1];
        const uint32_t wsrc[8] = {lo4.x, lo4.y, lo4.z, lo4.w, hi4.x, hi4.y, hi4.z, hi4.w};
        uint32_t neg = 0u;
        #pragma unroll
        for (int d = 0; d < 8; ++d) {
            #pragma unroll
            for (int qq = 0; qq < 4; ++qq) {
                const int ch = d*4 + qq;
                const int v = (int)((int8_t)(wsrc[d] >> (8*qq)));
                neg |= ((uint32_t)(v - sT1[wv][ch]) >> 31) << ch;   // 1 iff v<T
            }
        }
        ((uint32_t*)&BwU[wv][r][0])[c] = neg ^ flipn1;
    }
    // compute phase — wave-local: lane = out-channel, unrolled 64 positions
    int s = 0, q = 0;
    #pragma unroll
    for (int i = 0; i < 8; ++i) {
        uint32_t packA = 0u;
        #pragma unroll
        for (int j = 0; j < 8; ++j) {
            int D = 0, nw = 0;
            #pragma unroll
            for (int u = 0; u < 4; ++u) {
                const int r = 2*i + u - 2;
                if (r < 0 || r > 13) continue;           // compile-time
                const ull* row = &BwU[wv][r][0];
                if (j >= 1) { D += __popcll(row[j-1] ^ W[2*u+0]); ++nw; }
                if (j <= 6) { D += __popcll(row[j]   ^ W[2*u+1]); ++nw; }
            }
            const int o = 32*nw - D;                     // = full/2, exact
            s += o; q += o*o;
            packA |= (uint32_t)(o & 255) << (8*(j & 3));
            if ((j & 3) == 3) { cw[wv][lane][2*i + (j >> 2)] = packA; packA = 0u; }
        }
    }
    atomicAdd(&ssum[lane], s);
    atomicAdd(&ssq[lane], q);
    {   // coalesced writeout [n][ch][pos] — wave-local, dword-wise
        uint32_t* dst = (uint32_t*)(c2out + (size_t)n*4096);
        #pragma unroll
        for (int t = 0; t < 16; ++t) {
            const int g = t*64 + lane;
            dst[g] = cw[wv][g >> 4][g & 15];
        }
    }
    __syncthreads();          // barrier 2: all waves' stats in ssum/ssq
    if (tid < 64) {
        const int shard = blockIdx.x & 7;
        atomicAdd(&stats2[(shard*64 + tid)*2 + 0], (ull)(long long)ssum[tid]);
        atomicAdd(&stats2[(shard*64 + tid)*2 + 1], (ull)(long long)ssq[tid]);
    }
}

// ------------------------------------------------------------------
// KC: per-lane BN2 thresholds (lane=ch, registers only), binarize
// arithmetically, fc xor+popc, packed shuffle reduction, BN3 stats.
// 1 wave = 1 image.
// ------------------------------------------------------------------
__global__ __launch_bounds__(256) void kC_fc(
    const int8_t* __restrict__ c2o, const float* __restrict__ gm2,
    const float* __restrict__ bt2, const ull* __restrict__ stats2,
    const ull* __restrict__ w3b,
    int* __restrict__ fc, ull* __restrict__ stats3)
{
    __shared__ int fco[4][10];
    __shared__ int s3[10], q3[10];
    const int tid = threadIdx.x, lane = tid & 63, wv = tid >> 6;
    if (tid < 10) { s3[tid] = 0; q3[tid] = 0; }
    // per-lane BN2 threshold for own channel (values stored are o/2)
    int T2, fl;
    {
        long long ss = 0, qq = 0;
        for (int sh = 0; sh < 8; ++sh) {
            ss += (long long)stats2[(sh*64 + lane)*2 + 0];
            qq += (long long)stats2[(sh*64 + lane)*2 + 1];
        }
        const double N = 8192.0 * 64.0;
        const double mh = (double)ss / N;
        const double vh = (double)qq / N - mh*mh;
        const double a = (double)gm2[lane] / sqrt(4.0*vh + 1e-5);
        const double b = (double)bt2[lane] - 2.0*mh*a;
        int T; mk_thresh(2.0*a, b, T, fl);
        T2 = clampT(T, 200);
    }
    const ull flipn2 = ~__ballot(fl != 0);
    const int n = blockIdx.x*4 + wv;
    // load own channel's 64 bytes, build bit-word arithmetically
    const uint4* src = (const uint4*)(c2o + (size_t)n*4096 + lane*64);
    uint32_t neglo = 0u, neghi = 0u;
    #pragma unroll
    for (int r4 = 0; r4 < 4; ++r4) {
        const uint4 v4 = src[r4];
        const uint32_t wsrc[4] = {v4.x, v4.y, v4.z, v4.w};
        #pragma unroll
        for (int c = 0; c < 4; ++c) {
            #pragma unroll
            for (int b = 0; b < 4; ++b) {
                const int p = r4*16 + c*4 + b;
                const int v = (int)((int8_t)(wsrc[c] >> (8*b)));
                const uint32_t bit = (uint32_t)(v - T2) >> 31;   // 1 iff v<T
                if (p < 32) neglo |= bit << p; else neghi |= bit << (p - 32);
            }
        }
    }
    const ull myw = ((ull)neglo | ((ull)neghi << 32)) ^ flipn2;
    // 10 outputs: popc of mismatch vs w3 words (global, L2-hot), packed reduce
    uint32_t pk[5];
    #pragma unroll
    for (int t = 0; t < 5; ++t) {
        const uint32_t pa = (uint32_t)__popcll(myw ^ w3b[(2*t+0)*64 + lane]);
        const uint32_t pb = (uint32_t)__popcll(myw ^ w3b[(2*t+1)*64 + lane]);
        pk[t] = pa | (pb << 16);
    }
    #pragma unroll
    for (int off = 32; off >= 1; off >>= 1) {
        #pragma unroll
        for (int t = 0; t < 5; ++t) pk[t] += __shfl_xor(pk[t], off);
    }
    if (lane == 0) {
        #pragma unroll
        for (int m = 0; m < 10; ++m) {
            const int tot = (pk[m >> 1] >> (16*(m & 1))) & 0xFFFF;
            fco[wv][m] = 4096 - 2*tot;
        }
    }
    __syncthreads();          // barrier 1: fco + s3 zeros
    if (tid < 40) {
        const int li = tid / 10, m = tid - li*10;
        const int o = fco[li][m];
        fc[(size_t)(blockIdx.x*4 + li)*10 + m] = o;
        atomicAdd(&s3[m], o);
        atomicAdd(&q3[m], o*o);
    }
    __syncthreads();          // barrier 2
    if (tid < 10) {
        const int shard = blockIdx.x & 7;
        atomicAdd(&stats3[(shard*10 + tid)*2 + 0], (ull)(long long)s3[tid]);
        atomicAdd(&stats3[(shard*10 + tid)*2 + 1], (ull)(long long)q3[tid]);
    }
}

// ------------------------------------------------------------------
// KD: reduce BN3 stats (per block, redundant) + apply -> d_out (fp32)
// ------------------------------------------------------------------
__global__ __launch_bounds__(256) void kD_apply(
    const int* __restrict__ fc, const float* __restrict__ gm3,
    const float* __restrict__ bt3, const ull* __restrict__ stats3,
    float* __restrict__ out)
{
    __shared__ float a3[10], b3[10];
    const int tid = threadIdx.x;
    if (tid < 10) {
        long long s = 0, q = 0;
        for (int sh = 0; sh < 8; ++sh) {
            s += (long long)stats3[(sh*10 + tid)*2 + 0];
            q += (long long)stats3[(sh*10 + tid)*2 + 1];
        }
        const double N = 8192.0;
        const double mean = (double)s / N;
        const double var  = (double)q / N - mean*mean;
        const double a = (double)gm3[tid] / sqrt(var + 1e-5);
        a3[tid] = (float)a;
        b3[tid] = (float)((double)bt3[tid] - mean*a);
    }
    __syncthreads();
    const int e = blockIdx.x*256 + tid;
    if (e < NB*10) {
        const int m = e % 10;
        out[e] = fmaf(a3[m], (float)fc[e], b3[m]);
    }
}

extern "C" void kernel_launch(void* const* d_in, const int* in_sizes, int n_in,
                              void* d_out, int out_size, void* d_ws, size_t ws_size,
                              hipStream_t stream)
{
    const float* x   = (const float*)d_in[0];
    const float* w1  = (const float*)d_in[1];
    const float* gm1 = (const float*)d_in[2];
    const float* bt1 = (const float*)d_in[3];
    const float* w2  = (const float*)d_in[4];
    const float* gm2 = (const float*)d_in[5];
    const float* bt2 = (const float*)d_in[6];
    const float* w3  = (const float*)d_in[7];
    const float* gm3 = (const float*)d_in[8];
    const float* bt3 = (const float*)d_in[9];
    char* ws = (char*)d_ws;
    int8_t* c1o = (int8_t*)(ws + OFF_C1);
    int8_t* c2o = (int8_t*)(ws + OFF_C2);
    int*    fcb = (int*)(ws + OFF_FC);
    int*    s1  = (int*)(ws + OFF_S1);
    ull*    s2  = (ull*)(ws + OFF_S2);
    ull*    s3  = (ull*)(ws + OFF_S3);
    ull*    w2bp = (ull*)(ws + OFF_W2B);
    ull*    w3bp = (ull*)(ws + OFF_W3B);

    hipMemsetAsync(ws + OFF_S1, 0, 12288, stream);
    kA_conv1<<<2049, 256, 0, stream>>>(x, w1, w2, w3, c1o, s1, w2bp, w3bp);
    kB_conv2<<<2048, 256, 0, stream>>>(c1o, s1, gm1, bt1, w2bp, c2o, s2);
    kC_fc   <<<2048, 256, 0, stream>>>(c2o, gm2, bt2, s2, w3bp, fcb, s3);
    kD_apply<<<320,  256, 0, stream>>>(fcb, gm3, bt3, s3, (float*)d_out);
}